// Round 10
// baseline (39.479 us; speedup 1.0000x reference)
//
#include <hip/hip_runtime.h>
#include <math.h>

// FrequencyAdaptiveNorm: multi-scale (w=5,10,20) centered sliding-window
// normalization over L, softmax-weighted fusion.
// x: (B=32, L=2048, F=256) f32, weights: (3,) f32, out: same shape.
//
// v10 = v9 math + ZERO-MOV circular buffer. v9 counter arithmetic: 88
// wave-insts/elem measured vs ~50 audited -> ~23 v_mov/elem from the ring
// shift (VGPR=32 shows fixed-reg ring, no renaming). Here the delay line is
// slot[32] with compile-time (t+k)&31 indexing under full unroll: no shift
// exists in source, registers are fixed, insert x[j+20] is consumed 10
// iterations later (latency covered). All indices literal (no scratch,
// rule-20 safe). Edge blocks (2/64) keep the v9 checked shifting path.

#define B_ 32
#define L_ 2048
#define F_ 256
#define TL 32     // L-chunk per block; grid = (64, 32) = 2048 blocks
#define NR 32     // circular buffer slots; slot[m&31] = x[l0-10+m]
#define PRE 30    // prefilled slots m = 0..29

#define RSQ(x) __builtin_amdgcn_rsqf(x)   // single v_rsq_f32, ~1 ulp

__device__ __forceinline__ float fin(float v) {
    return isfinite(v) ? v : 0.0f;   // nan_to_num(nan=0, +inf=0, -inf=0)
}

// ---------------- interior: circular-buffer fast path ----------------------
__device__ __forceinline__ void run_interior(const float* __restrict__ xb,
                                             float* __restrict__ ob,
                                             const int l0,
                                             const float ws5, const float ws10,
                                             const float ws20) {
    const float eps = 1e-5f;
    const float* xr = xb + (l0 - 10) * F_;   // xr[m*F_] = x[l0-10+m]
    float*       obr = ob + l0 * F_;

    // prefill slots m = 0..PRE-1 (one burst of independent loads)
    float slot[NR];
#pragma unroll
    for (int m = 0; m < PRE; ++m) slot[m] = fin(xr[m * F_]);

    // running sums at j=l0: w20 = m 0..19, w10 = m 5..14, w5 = m 8..12
    float s5 = 0.f, q5 = 0.f, s10 = 0.f, q10 = 0.f, s20 = 0.f, q20 = 0.f;
#pragma unroll
    for (int m = 0; m < 20; ++m) { s20 += slot[m]; q20 = fmaf(slot[m], slot[m], q20); }
#pragma unroll
    for (int m = 5; m < 15; ++m) { s10 += slot[m]; q10 = fmaf(slot[m], slot[m], q10); }
#pragma unroll
    for (int m = 8; m < 13; ++m) { s5  += slot[m]; q5  = fmaf(slot[m], slot[m], q5);  }

#pragma unroll
    for (int t = 0; t < TL; ++t) {
        // insert m = t+PRE (x[j+20]), consumed 10 iterations later.
        // max m needed = (TL-1)+20 = 51 -> insert only while t+PRE <= 51.
        if (t + PRE < TL + 20)
            slot[(t + PRE) & (NR - 1)] = fin(xr[(t + PRE) * F_]);

        const float xc = slot[(t + 10) & (NR - 1)];
        float acc;
        {   // w=5
            const float mean = s5 * 0.2f, mean2 = q5 * 0.2f;
            const float var  = fmaxf(fmaf(-mean, mean, mean2), 0.0f);
            acc = ws5 * ((xc - mean) * RSQ(var + eps));
        }
        {   // w=10
            const float mean = s10 * 0.1f, mean2 = q10 * 0.1f;
            const float var  = fmaxf(fmaf(-mean, mean, mean2), 0.0f);
            acc = fmaf(ws10, (xc - mean) * RSQ(var + eps), acc);
        }
        {   // w=20
            const float mean = s20 * 0.05f, mean2 = q20 * 0.05f;
            const float var  = fmaxf(fmaf(-mean, mean, mean2), 0.0f);
            acc = fmaf(ws20, (xc - mean) * RSQ(var + eps), acc);
        }
        obr[t * F_] = acc;

        // slide j -> j+1:  s += a-r;  q += (a-r)(a+r)   (static slot reads)
        if (t < TL - 1) {
            {
                const float a = slot[(t + 13) & (NR - 1)], r = slot[(t + 8) & (NR - 1)];
                const float d = a - r, p = a + r;
                s5 += d; q5 = fmaf(d, p, q5);
            }
            {
                const float a = slot[(t + 15) & (NR - 1)], r = slot[(t + 5) & (NR - 1)];
                const float d = a - r, p = a + r;
                s10 += d; q10 = fmaf(d, p, q10);
            }
            {
                const float a = slot[(t + 20) & (NR - 1)], r = slot[t & (NR - 1)];
                const float d = a - r, p = a + r;
                s20 += d; q20 = fmaf(d, p, q20);
            }
        }
    }
}

// ---------------- edge: checked shifting-ring path (blocks 0, 63) ----------
__device__ __forceinline__ void run_edge(const float* __restrict__ xb,
                                         float* __restrict__ ob,
                                         const int l0,
                                         const float ws5, const float ws10,
                                         const float ws20) {
    const float eps = 1e-5f;
    float ring[21];
#pragma unroll
    for (int d = 0; d < 21; ++d) {
        const int l = l0 - 10 + d;
        ring[d] = ((unsigned)l < (unsigned)L_) ? fin(xb[l * F_]) : 0.0f;
    }
    float s5 = 0.f, q5 = 0.f, s10 = 0.f, q10 = 0.f, s20 = 0.f, q20 = 0.f;
#pragma unroll
    for (int d = 0; d < 20; ++d) { s20 += ring[d]; q20 = fmaf(ring[d], ring[d], q20); }
#pragma unroll
    for (int d = 5; d < 15; ++d) { s10 += ring[d]; q10 = fmaf(ring[d], ring[d], q10); }
#pragma unroll
    for (int d = 8; d < 13; ++d) { s5  += ring[d]; q5  = fmaf(ring[d], ring[d], q5);  }

#pragma unroll
    for (int t = 0; t < TL; ++t) {
        const int j = l0 + t;
        const int ln = j + 11;
        const float vnew = ((unsigned)ln < (unsigned)L_) ? fin(xb[ln * F_]) : 0.0f;

        const float xc = ring[10];
        float acc = 0.0f;
        if (j >= 2 && j <= L_ - 3) {
            const float mean = s5 * 0.2f, mean2 = q5 * 0.2f;
            const float var  = fmaxf(fmaf(-mean, mean, mean2), 0.0f);
            acc = fmaf(ws5, (xc - mean) * RSQ(var + eps), acc);
        }
        if (j >= 5 && j <= L_ - 5) {
            const float mean = s10 * 0.1f, mean2 = q10 * 0.1f;
            const float var  = fmaxf(fmaf(-mean, mean, mean2), 0.0f);
            acc = fmaf(ws10, (xc - mean) * RSQ(var + eps), acc);
        }
        if (j >= 10 && j <= L_ - 10) {
            const float mean = s20 * 0.05f, mean2 = q20 * 0.05f;
            const float var  = fmaxf(fmaf(-mean, mean, mean2), 0.0f);
            acc = fmaf(ws20, (xc - mean) * RSQ(var + eps), acc);
        }
        ob[j * F_] = acc;

        { const float a = ring[13], r = ring[8];  const float d = a - r, p = a + r; s5  += d; q5  = fmaf(d, p, q5);  }
        { const float a = ring[15], r = ring[5];  const float d = a - r, p = a + r; s10 += d; q10 = fmaf(d, p, q10); }
        { const float a = ring[20], r = ring[0];  const float d = a - r, p = a + r; s20 += d; q20 = fmaf(d, p, q20); }

#pragma unroll
        for (int d = 0; d < 20; ++d) ring[d] = ring[d + 1];
        ring[20] = vnew;
    }
}

__global__ __launch_bounds__(256, 8)
void fan_kernel(const float* __restrict__ x,
                const float* __restrict__ w,
                float* __restrict__ out) {
    const int f  = threadIdx.x;           // 0..255 == F
    const int b  = blockIdx.y;
    const int l0 = blockIdx.x * TL;
    const float* xb = x   + (size_t)b * L_ * F_ + f;
    float*       ob = out + (size_t)b * L_ * F_ + f;

    // softmax over the 3 fusion logits (uniform across threads)
    const float w0 = w[0], w1 = w[1], w2 = w[2];
    const float m  = fmaxf(w0, fmaxf(w1, w2));
    const float e0 = expf(w0 - m), e1 = expf(w1 - m), e2 = expf(w2 - m);
    const float inv = 1.0f / (e0 + e1 + e2);
    const float ws5 = e0 * inv, ws10 = e1 * inv, ws20 = e2 * inv;

    // interior blocks 1..62: loads span [l0-10, l0+41] -> in range, and all
    // three window validity ranges cover every j in the chunk.
    if (blockIdx.x != 0 && blockIdx.x != gridDim.x - 1)
        run_interior(xb, ob, l0, ws5, ws10, ws20);
    else
        run_edge(xb, ob, l0, ws5, ws10, ws20);
}

extern "C" void kernel_launch(void* const* d_in, const int* in_sizes, int n_in,
                              void* d_out, int out_size, void* d_ws, size_t ws_size,
                              hipStream_t stream) {
    const float* x = (const float*)d_in[0];
    const float* w = (const float*)d_in[1];
    float* out = (float*)d_out;
    (void)in_sizes; (void)n_in; (void)out_size; (void)d_ws; (void)ws_size;

    dim3 grid(L_ / TL, B_);   // (64, 32) = 2048 blocks
    dim3 block(F_);           // 256 threads, one per feature column
    hipLaunchKernelGGL(fan_kernel, grid, block, 0, stream, x, w, out);
}